// Round 4
// baseline (1752.954 us; speedup 1.0000x reference)
//
#include <hip/hip_runtime.h>

#define D 128        // D_IN
#define DOUT 64
#define BN_EPS 1e-5f

typedef unsigned int   u32;
typedef unsigned short u16;

// bf16 helpers (compute stays fp32; storage is bf16 to halve random-gather lines)
__device__ __forceinline__ u16 f2bf(float f) {
    u32 x = __float_as_uint(f);
    x += 0x7fffu + ((x >> 16) & 1u);     // round-to-nearest-even
    return (u16)(x >> 16);
}
__device__ __forceinline__ float bflo(u32 u) { return __uint_as_float(u << 16); }
__device__ __forceinline__ float bfhi(u32 u) { return __uint_as_float(u & 0xffff0000u); }

// ---------------------------------------------------------------------------
// One-dispatch init: convert x -> bf16, zero deg, init stats (slot0 scale=1),
// zero the bump counter.
// ---------------------------------------------------------------------------
__global__ void init_kernel(const float* __restrict__ x, u16* __restrict__ xb,
                            int* __restrict__ deg, int* __restrict__ counter,
                            float* __restrict__ stats, int n_nodes) {
    int total = n_nodes * (D / 4);       // one thread = 4 features
    for (int t = blockIdx.x * blockDim.x + threadIdx.x; t < total;
         t += gridDim.x * blockDim.x) {
        float4 v = ((const float4*)x)[t];
        ((ushort4*)xb)[t] = make_ushort4(f2bf(v.x), f2bf(v.y), f2bf(v.z), f2bf(v.w));
        if (t < n_nodes) deg[t] = 0;
        if (t < 2048) stats[t] = (t >= 256 && t < 384) ? 1.f : 0.f;
        if (t == 0) *counter = 0;
    }
}

__global__ void hist_kernel(const int* __restrict__ ei, int* __restrict__ deg,
                            int n_edges) {
    for (int e = blockIdx.x * blockDim.x + threadIdx.x; e < n_edges;
         e += gridDim.x * blockDim.x)
        atomicAdd(&deg[ei[e]], 1);
}

// ---------------------------------------------------------------------------
// Bucket allocation WITHOUT a global scan: wave-level prefix + one atomic
// per wave. Bucket order is arbitrary (doesn't matter for the aggregation).
// start[i] fixed; cursor[i] is the bump copy consumed by fill.
// ---------------------------------------------------------------------------
__global__ void alloc_kernel(const int* __restrict__ deg, int* __restrict__ start,
                             int* __restrict__ cursor, int* __restrict__ counter,
                             int n) {
    int i = blockIdx.x * blockDim.x + threadIdx.x;
    int lane = threadIdx.x & 63;
    int d = (i < n) ? deg[i] : 0;
    int s = d;
    #pragma unroll
    for (int off = 1; off < 64; off <<= 1) {
        int t = __shfl_up(s, off, 64);
        if (lane >= off) s += t;
    }
    int base = 0;
    if (lane == 63) base = atomicAdd(counter, s);
    base = __shfl(base, 63, 64);
    if (i < n) {
        int st = base + s - d;
        start[i] = st;
        cursor[i] = st;
    }
}

__global__ void fill_kernel(const int* __restrict__ ei, int* __restrict__ cursor,
                            int* __restrict__ srcs, int n_edges) {
    for (int e = blockIdx.x * blockDim.x + threadIdx.x; e < n_edges;
         e += gridDim.x * blockDim.x) {
        int d = ei[e];
        int s = ei[n_edges + e];
        int p = atomicAdd(&cursor[d], 1);
        srcs[p] = s;
    }
}

// ---------------------------------------------------------------------------
// Fused layer: v[i] = norm(h[i]) + sum_j norm(h[j]); accumulate per-feature
// sum/sumsq of v (fp32). h is bf16 [N,128]; v written as bf16. norm =
// relu(x*scale_prev+shift_prev), identity for layer 0 (the reference's
// readout term cancels inside BN and is omitted).
// Block = 16 groups x 16 lanes; lane owns 8 features (16-B uint4 loads, one
// row = 256 B = 2 lines). Gather loop 8-wide pipelined.
// ---------------------------------------------------------------------------
template <bool APPLY>
__global__ void agg_kernel(const u16* __restrict__ h,
                           const int* __restrict__ srcs,
                           const int* __restrict__ start,
                           const int* __restrict__ deg,
                           const float* __restrict__ stats_prev,
                           float* __restrict__ stats_cur,
                           u16* __restrict__ vout,
                           int n_nodes) {
    const int lane = threadIdx.x & 15;
    const int grp  = threadIdx.x >> 4;
    const int c    = lane << 3;          // feature start (8 per lane)
    float sc[8], sh[8];
    #pragma unroll
    for (int k = 0; k < 8; ++k) {
        sc[k] = stats_prev[256 + c + k];
        sh[k] = stats_prev[384 + c + k];
    }
    float sum[8], sq[8];
    #pragma unroll
    for (int k = 0; k < 8; ++k) { sum[k] = 0.f; sq[k] = 0.f; }
    const int stride = gridDim.x * 16;
    float a[8];

#define ACC(u_) do { \
    float f0 = bflo((u_).x), f1 = bfhi((u_).x), f2 = bflo((u_).y), f3 = bfhi((u_).y); \
    float f4 = bflo((u_).z), f5 = bfhi((u_).z), f6 = bflo((u_).w), f7 = bfhi((u_).w); \
    if (APPLY) { \
        a[0] += fmaxf(fmaf(f0, sc[0], sh[0]), 0.f); \
        a[1] += fmaxf(fmaf(f1, sc[1], sh[1]), 0.f); \
        a[2] += fmaxf(fmaf(f2, sc[2], sh[2]), 0.f); \
        a[3] += fmaxf(fmaf(f3, sc[3], sh[3]), 0.f); \
        a[4] += fmaxf(fmaf(f4, sc[4], sh[4]), 0.f); \
        a[5] += fmaxf(fmaf(f5, sc[5], sh[5]), 0.f); \
        a[6] += fmaxf(fmaf(f6, sc[6], sh[6]), 0.f); \
        a[7] += fmaxf(fmaf(f7, sc[7], sh[7]), 0.f); \
    } else { \
        a[0] += f0; a[1] += f1; a[2] += f2; a[3] += f3; \
        a[4] += f4; a[5] += f5; a[6] += f6; a[7] += f7; \
    } } while (0)

    for (int i = blockIdx.x * 16 + grp; i < n_nodes; i += stride) {
        int off = start[i];
        int dg  = deg[i];
        {   // self term
            uint4 u = *(const uint4*)(h + ((size_t)i << 7) + c);
            float f0 = bflo(u.x), f1 = bfhi(u.x), f2 = bflo(u.y), f3 = bfhi(u.y);
            float f4 = bflo(u.z), f5 = bfhi(u.z), f6 = bflo(u.w), f7 = bfhi(u.w);
            float ff[8] = {f0, f1, f2, f3, f4, f5, f6, f7};
            #pragma unroll
            for (int k = 0; k < 8; ++k)
                a[k] = APPLY ? fmaxf(fmaf(ff[k], sc[k], sh[k]), 0.f) : ff[k];
        }
        for (int base = 0; base < dg; base += 16) {
            int cnt = min(dg - base, 16);
            int sv = (lane < cnt) ? srcs[off + base + lane] : 0;
            int k = 0;
            for (; k + 8 <= cnt; k += 8) {
                uint4 b0, b1, b2, b3, b4, b5, b6, b7;
                {
                    int j0 = __shfl(sv, k + 0, 16), j1 = __shfl(sv, k + 1, 16);
                    int j2 = __shfl(sv, k + 2, 16), j3 = __shfl(sv, k + 3, 16);
                    int j4 = __shfl(sv, k + 4, 16), j5 = __shfl(sv, k + 5, 16);
                    int j6 = __shfl(sv, k + 6, 16), j7 = __shfl(sv, k + 7, 16);
                    b0 = *(const uint4*)(h + ((size_t)j0 << 7) + c);
                    b1 = *(const uint4*)(h + ((size_t)j1 << 7) + c);
                    b2 = *(const uint4*)(h + ((size_t)j2 << 7) + c);
                    b3 = *(const uint4*)(h + ((size_t)j3 << 7) + c);
                    b4 = *(const uint4*)(h + ((size_t)j4 << 7) + c);
                    b5 = *(const uint4*)(h + ((size_t)j5 << 7) + c);
                    b6 = *(const uint4*)(h + ((size_t)j6 << 7) + c);
                    b7 = *(const uint4*)(h + ((size_t)j7 << 7) + c);
                }
                ACC(b0); ACC(b1); ACC(b2); ACC(b3);
                ACC(b4); ACC(b5); ACC(b6); ACC(b7);
            }
            for (; k < cnt; ++k) {
                int j0 = __shfl(sv, k, 16);
                uint4 b0 = *(const uint4*)(h + ((size_t)j0 << 7) + c);
                ACC(b0);
            }
        }
        // store v (bf16) + fp32 stats accumulation
        uint4 w;
        w.x = (u32)f2bf(a[0]) | ((u32)f2bf(a[1]) << 16);
        w.y = (u32)f2bf(a[2]) | ((u32)f2bf(a[3]) << 16);
        w.z = (u32)f2bf(a[4]) | ((u32)f2bf(a[5]) << 16);
        w.w = (u32)f2bf(a[6]) | ((u32)f2bf(a[7]) << 16);
        *(uint4*)(vout + ((size_t)i << 7) + c) = w;
        #pragma unroll
        for (int k = 0; k < 8; ++k) { sum[k] += a[k]; sq[k] += a[k] * a[k]; }
    }
#undef ACC

    // block reduce (two passes over one 8 KB buffer), then atomics
    __shared__ float red[16][16][8];
    #pragma unroll
    for (int k = 0; k < 8; ++k) red[grp][lane][k] = sum[k];
    __syncthreads();
    for (int m = 8; m >= 1; m >>= 1) {
        if (grp < m) {
            #pragma unroll
            for (int k = 0; k < 8; ++k) red[grp][lane][k] += red[grp + m][lane][k];
        }
        __syncthreads();
    }
    if (grp == 0) {
        #pragma unroll
        for (int k = 0; k < 8; ++k) unsafeAtomicAdd(&stats_cur[c + k], red[0][lane][k]);
    }
    __syncthreads();
    #pragma unroll
    for (int k = 0; k < 8; ++k) red[grp][lane][k] = sq[k];
    __syncthreads();
    for (int m = 8; m >= 1; m >>= 1) {
        if (grp < m) {
            #pragma unroll
            for (int k = 0; k < 8; ++k) red[grp][lane][k] += red[grp + m][lane][k];
        }
        __syncthreads();
    }
    if (grp == 0) {
        #pragma unroll
        for (int k = 0; k < 8; ++k)
            unsafeAtomicAdd(&stats_cur[128 + c + k], red[0][lane][k]);
    }
}

__global__ void finalize_stats_kernel(float* __restrict__ stats_cur,
                                      const float* __restrict__ gamma,
                                      const float* __restrict__ beta,
                                      int layer, float inv_n) {
    int f = threadIdx.x;
    float mean = stats_cur[f] * inv_n;
    float var  = stats_cur[128 + f] * inv_n - mean * mean;
    var = fmaxf(var, 0.f);
    float s = gamma[layer * D + f] * rsqrtf(var + BN_EPS);
    stats_cur[256 + f] = s;
    stats_cur[384 + f] = beta[layer * D + f] - mean * s;
}

// ---------------------------------------------------------------------------
// out[N,64] = relu(norm3(v2_bf16)) @ W + b. 16 rows/block, W in LDS.
// ---------------------------------------------------------------------------
__global__ void head_kernel(const u16* __restrict__ v2,
                            const float* __restrict__ stats3,
                            const float* __restrict__ W,
                            const float* __restrict__ b,
                            float* __restrict__ out, int n_nodes) {
    __shared__ float Ws[D * DOUT];
    __shared__ float scs[D];
    __shared__ float shs[D];
    for (int i = threadIdx.x; i < D * DOUT; i += 256) Ws[i] = W[i];
    if (threadIdx.x < D) {
        scs[threadIdx.x] = stats3[256 + threadIdx.x];
        shs[threadIdx.x] = stats3[384 + threadIdx.x];
    }
    __syncthreads();
    int col = threadIdx.x & (DOUT - 1);
    int rg  = threadIdx.x >> 6;
    float bb = b[col];
    int r0 = blockIdx.x * 16 + rg * 4;
    #pragma unroll
    for (int rr = 0; rr < 4; ++rr) {
        int r = r0 + rr;
        if (r >= n_nodes) return;
        const uint2* hr = (const uint2*)(v2 + ((size_t)r << 7));
        float acc = bb;
        #pragma unroll
        for (int k4 = 0; k4 < 32; ++k4) {
            uint2 u = hr[k4];
            int k = k4 * 4;
            float f0 = bflo(u.x), f1 = bfhi(u.x), f2 = bflo(u.y), f3 = bfhi(u.y);
            float w0 = fmaxf(fmaf(f0, scs[k + 0], shs[k + 0]), 0.f);
            float w1 = fmaxf(fmaf(f1, scs[k + 1], shs[k + 1]), 0.f);
            float w2 = fmaxf(fmaf(f2, scs[k + 2], shs[k + 2]), 0.f);
            float w3 = fmaxf(fmaf(f3, scs[k + 3], shs[k + 3]), 0.f);
            acc = fmaf(w0, Ws[(k + 0) * DOUT + col], acc);
            acc = fmaf(w1, Ws[(k + 1) * DOUT + col], acc);
            acc = fmaf(w2, Ws[(k + 2) * DOUT + col], acc);
            acc = fmaf(w3, Ws[(k + 3) * DOUT + col], acc);
        }
        out[(size_t)r * DOUT + col] = acc;
    }
}

extern "C" void kernel_launch(void* const* d_in, const int* in_sizes, int n_in,
                              void* d_out, int out_size, void* d_ws, size_t ws_size,
                              hipStream_t stream) {
    const float* x     = (const float*)d_in[0];
    const int*   ei    = (const int*)d_in[1];
    const float* gamma = (const float*)d_in[2];
    const float* beta  = (const float*)d_in[3];
    const float* W     = (const float*)d_in[4];
    const float* bvec  = (const float*)d_in[5];
    float* out = (float*)d_out;

    const int n_nodes = in_sizes[0] / D;     // 100000
    const int n_edges = in_sizes[1] / 2;     // 1600000

    const size_t row_bytes = (size_t)n_nodes * D * sizeof(u16);   // 25.6 MB
    char* p = (char*)d_ws;
    u16*   xb     = (u16*)p;   p += row_bytes;
    u16*   vA     = (u16*)p;   p += row_bytes;
    u16*   vB     = (u16*)p;   p += row_bytes;
    int*   srcs   = (int*)p;   p += (size_t)n_edges * sizeof(int);
    int*   deg    = (int*)p;   p += (size_t)n_nodes * sizeof(int);
    int*   start  = (int*)p;   p += (size_t)n_nodes * sizeof(int);
    int*   cursor = (int*)p;   p += (size_t)n_nodes * sizeof(int);
    int*   counter= (int*)p;   p += 256;
    float* stats  = (float*)p; // 4 * 512 floats

    const float inv_n = 1.0f / (float)n_nodes;

    // --- init + CSR build (once per call) ---
    init_kernel<<<2048, 256, 0, stream>>>(x, xb, deg, counter, stats, n_nodes);
    hist_kernel<<<1024, 256, 0, stream>>>(ei, deg, n_edges);
    alloc_kernel<<<(n_nodes + 255) / 256, 256, 0, stream>>>(deg, start, cursor,
                                                            counter, n_nodes);
    fill_kernel<<<1024, 256, 0, stream>>>(ei, cursor, srcs, n_edges);

    // --- 3 fused layers ---
    const u16* h = xb;
    u16* vout = vA;
    for (int L = 0; L < 3; ++L) {
        float* scur = stats + (size_t)(L + 1) * 512;
        const float* sprev = stats + (size_t)L * 512;
        if (L == 0)
            agg_kernel<false><<<2048, 256, 0, stream>>>(h, srcs, start, deg,
                sprev, scur, vout, n_nodes);
        else
            agg_kernel<true><<<2048, 256, 0, stream>>>(h, srcs, start, deg,
                sprev, scur, vout, n_nodes);
        finalize_stats_kernel<<<1, D, 0, stream>>>(scur, gamma, beta, L, inv_n);
        h = vout;
        vout = (vout == vA) ? vB : vA;
    }

    // --- head: inline norm of layer 2 + matmul ---
    head_kernel<<<(n_nodes + 15) / 16, 256, 0, stream>>>(h, stats + 3 * 512, W,
                                                         bvec, out, n_nodes);
}

// Round 5
// 1281.009 us; speedup vs baseline: 1.3684x; 1.3684x over previous
//
#include <hip/hip_runtime.h>

#define D 128        // D_IN
#define DOUT 64
#define BN_EPS 1e-5f

typedef unsigned int   u32;
typedef unsigned short u16;

// bf16 helpers (compute stays fp32; storage is bf16 to halve random-gather lines)
__device__ __forceinline__ u16 f2bf(float f) {
    u32 x = __float_as_uint(f);
    x += 0x7fffu + ((x >> 16) & 1u);     // round-to-nearest-even
    return (u16)(x >> 16);
}
__device__ __forceinline__ float bflo(u32 u) { return __uint_as_float(u << 16); }
__device__ __forceinline__ float bfhi(u32 u) { return __uint_as_float(u & 0xffff0000u); }

// ---------------------------------------------------------------------------
// One-dispatch init: convert x -> bf16, zero deg, init stats (slot0 scale=1),
// zero the bump counter.
// ---------------------------------------------------------------------------
__global__ void init_kernel(const float* __restrict__ x, u16* __restrict__ xb,
                            int* __restrict__ deg, int* __restrict__ counter,
                            float* __restrict__ stats, int n_nodes) {
    int total = n_nodes * (D / 4);       // one thread = 4 features
    for (int t = blockIdx.x * blockDim.x + threadIdx.x; t < total;
         t += gridDim.x * blockDim.x) {
        float4 v = ((const float4*)x)[t];
        ((ushort4*)xb)[t] = make_ushort4(f2bf(v.x), f2bf(v.y), f2bf(v.z), f2bf(v.w));
        if (t < n_nodes) deg[t] = 0;
        if (t < 2048) stats[t] = (t >= 256 && t < 384) ? 1.f : 0.f;
        if (t == 0) *counter = 0;
    }
}

__global__ void hist_kernel(const int* __restrict__ ei, int* __restrict__ deg,
                            int n_edges) {
    for (int e = blockIdx.x * blockDim.x + threadIdx.x; e < n_edges;
         e += gridDim.x * blockDim.x)
        atomicAdd(&deg[ei[e]], 1);
}

// ---------------------------------------------------------------------------
// Bucket allocation without a global scan: wave prefix + one atomic per wave.
// ---------------------------------------------------------------------------
__global__ void alloc_kernel(const int* __restrict__ deg, int* __restrict__ start,
                             int* __restrict__ cursor, int* __restrict__ counter,
                             int n) {
    int i = blockIdx.x * blockDim.x + threadIdx.x;
    int lane = threadIdx.x & 63;
    int d = (i < n) ? deg[i] : 0;
    int s = d;
    #pragma unroll
    for (int off = 1; off < 64; off <<= 1) {
        int t = __shfl_up(s, off, 64);
        if (lane >= off) s += t;
    }
    int base = 0;
    if (lane == 63) base = atomicAdd(counter, s);
    base = __shfl(base, 63, 64);
    if (i < n) {
        int st = base + s - d;
        start[i] = st;
        cursor[i] = st;
    }
}

__global__ void fill_kernel(const int* __restrict__ ei, int* __restrict__ cursor,
                            int* __restrict__ srcs, int n_edges) {
    for (int e = blockIdx.x * blockDim.x + threadIdx.x; e < n_edges;
         e += gridDim.x * blockDim.x) {
        int d = ei[e];
        int s = ei[n_edges + e];
        int p = atomicAdd(&cursor[d], 1);
        srcs[p] = s;
    }
}

// ---------------------------------------------------------------------------
// Per-bucket insertion sort by src (lists avg 16). Sorted lists make the
// k-th gather across concurrently-running groups cluster near the same
// quantile of node space -> per-XCD L2 locality on the random gather.
// ---------------------------------------------------------------------------
__global__ void sort_kernel(const int* __restrict__ start,
                            const int* __restrict__ deg,
                            int* __restrict__ srcs, int n) {
    int i = blockIdx.x * blockDim.x + threadIdx.x;
    if (i >= n) return;
    int s = start[i], d = deg[i];
    for (int a = 1; a < d; ++a) {
        int key = srcs[s + a];
        int b = a - 1;
        while (b >= 0 && srcs[s + b] > key) { srcs[s + b + 1] = srcs[s + b]; --b; }
        srcs[s + b + 1] = key;
    }
}

// ---------------------------------------------------------------------------
// Fused layer: v[i] = norm(h[i]) + sum_j norm(h[j]); accumulate per-feature
// sum/sumsq of v (fp32). h, v are bf16 [N,128]. norm = relu(x*sc+sh),
// identity for layer 0 (reference's readout term cancels inside BN).
// Block = 8 groups x 32 lanes; lane owns 4 features (uint2 = 8 B loads,
// row = 256 B = 2 lines). Gather 4-wide pipelined; ~8 data VGPRs in flight
// (R4's 8-wide uint4 version spilled at the 64-VGPR cap -> scratch traffic).
// ---------------------------------------------------------------------------
template <bool APPLY>
__global__ void agg_kernel(const u16* __restrict__ h,
                           const int* __restrict__ srcs,
                           const int* __restrict__ start,
                           const int* __restrict__ deg,
                           const float* __restrict__ stats_prev,
                           float* __restrict__ stats_cur,
                           u16* __restrict__ vout,
                           int n_nodes) {
    const int lane = threadIdx.x & 31;
    const int grp  = threadIdx.x >> 5;
    const int c    = lane << 2;          // 4 features per lane
    float sc[4], sh[4];
    #pragma unroll
    for (int k = 0; k < 4; ++k) {
        sc[k] = stats_prev[256 + c + k];
        sh[k] = stats_prev[384 + c + k];
    }
    float sum[4] = {0.f, 0.f, 0.f, 0.f};
    float sq[4]  = {0.f, 0.f, 0.f, 0.f};
    const int stride = gridDim.x * 8;
    float a[4];

#define ACC(u_) do { \
    float f0 = bflo((u_).x), f1 = bfhi((u_).x); \
    float f2 = bflo((u_).y), f3 = bfhi((u_).y); \
    if (APPLY) { \
        a[0] += fmaxf(fmaf(f0, sc[0], sh[0]), 0.f); \
        a[1] += fmaxf(fmaf(f1, sc[1], sh[1]), 0.f); \
        a[2] += fmaxf(fmaf(f2, sc[2], sh[2]), 0.f); \
        a[3] += fmaxf(fmaf(f3, sc[3], sh[3]), 0.f); \
    } else { \
        a[0] += f0; a[1] += f1; a[2] += f2; a[3] += f3; \
    } } while (0)

    for (int i = blockIdx.x * 8 + grp; i < n_nodes; i += stride) {
        int off = start[i];
        int dg  = deg[i];
        {   // self term
            uint2 u = *(const uint2*)(h + ((size_t)i << 7) + c);
            float f0 = bflo(u.x), f1 = bfhi(u.x);
            float f2 = bflo(u.y), f3 = bfhi(u.y);
            if (APPLY) {
                a[0] = fmaxf(fmaf(f0, sc[0], sh[0]), 0.f);
                a[1] = fmaxf(fmaf(f1, sc[1], sh[1]), 0.f);
                a[2] = fmaxf(fmaf(f2, sc[2], sh[2]), 0.f);
                a[3] = fmaxf(fmaf(f3, sc[3], sh[3]), 0.f);
            } else {
                a[0] = f0; a[1] = f1; a[2] = f2; a[3] = f3;
            }
        }
        for (int base = 0; base < dg; base += 32) {
            int cnt = min(dg - base, 32);
            int sv = (lane < cnt) ? srcs[off + base + lane] : 0;
            int k = 0;
            for (; k + 4 <= cnt; k += 4) {
                int j0 = __shfl(sv, k + 0, 32), j1 = __shfl(sv, k + 1, 32);
                int j2 = __shfl(sv, k + 2, 32), j3 = __shfl(sv, k + 3, 32);
                uint2 b0 = *(const uint2*)(h + ((size_t)j0 << 7) + c);
                uint2 b1 = *(const uint2*)(h + ((size_t)j1 << 7) + c);
                uint2 b2 = *(const uint2*)(h + ((size_t)j2 << 7) + c);
                uint2 b3 = *(const uint2*)(h + ((size_t)j3 << 7) + c);
                ACC(b0); ACC(b1); ACC(b2); ACC(b3);
            }
            for (; k < cnt; ++k) {
                int j0 = __shfl(sv, k, 32);
                uint2 b0 = *(const uint2*)(h + ((size_t)j0 << 7) + c);
                ACC(b0);
            }
        }
        uint2 w;
        w.x = (u32)f2bf(a[0]) | ((u32)f2bf(a[1]) << 16);
        w.y = (u32)f2bf(a[2]) | ((u32)f2bf(a[3]) << 16);
        *(uint2*)(vout + ((size_t)i << 7) + c) = w;
        #pragma unroll
        for (int k = 0; k < 4; ++k) { sum[k] += a[k]; sq[k] += a[k] * a[k]; }
    }
#undef ACC

    // block reduce (stride padded to 5 floats -> conflict-free), then atomics
    __shared__ float red[8][32][5];
    #pragma unroll
    for (int k = 0; k < 4; ++k) red[grp][lane][k] = sum[k];
    __syncthreads();
    for (int m = 4; m >= 1; m >>= 1) {
        if (grp < m) {
            #pragma unroll
            for (int k = 0; k < 4; ++k) red[grp][lane][k] += red[grp + m][lane][k];
        }
        __syncthreads();
    }
    if (grp == 0) {
        #pragma unroll
        for (int k = 0; k < 4; ++k)
            unsafeAtomicAdd(&stats_cur[c + k], red[0][lane][k]);
    }
    __syncthreads();
    #pragma unroll
    for (int k = 0; k < 4; ++k) red[grp][lane][k] = sq[k];
    __syncthreads();
    for (int m = 4; m >= 1; m >>= 1) {
        if (grp < m) {
            #pragma unroll
            for (int k = 0; k < 4; ++k) red[grp][lane][k] += red[grp + m][lane][k];
        }
        __syncthreads();
    }
    if (grp == 0) {
        #pragma unroll
        for (int k = 0; k < 4; ++k)
            unsafeAtomicAdd(&stats_cur[128 + c + k], red[0][lane][k]);
    }
}

__global__ void finalize_stats_kernel(float* __restrict__ stats_cur,
                                      const float* __restrict__ gamma,
                                      const float* __restrict__ beta,
                                      int layer, float inv_n) {
    int f = threadIdx.x;
    float mean = stats_cur[f] * inv_n;
    float var  = stats_cur[128 + f] * inv_n - mean * mean;
    var = fmaxf(var, 0.f);
    float s = gamma[layer * D + f] * rsqrtf(var + BN_EPS);
    stats_cur[256 + f] = s;
    stats_cur[384 + f] = beta[layer * D + f] - mean * s;
}

// ---------------------------------------------------------------------------
// out[N,64] = relu(norm3(v2_bf16)) @ W + b. 16 rows/block, W in LDS.
// ---------------------------------------------------------------------------
__global__ void head_kernel(const u16* __restrict__ v2,
                            const float* __restrict__ stats3,
                            const float* __restrict__ W,
                            const float* __restrict__ b,
                            float* __restrict__ out, int n_nodes) {
    __shared__ float Ws[D * DOUT];
    __shared__ float scs[D];
    __shared__ float shs[D];
    for (int i = threadIdx.x; i < D * DOUT; i += 256) Ws[i] = W[i];
    if (threadIdx.x < D) {
        scs[threadIdx.x] = stats3[256 + threadIdx.x];
        shs[threadIdx.x] = stats3[384 + threadIdx.x];
    }
    __syncthreads();
    int col = threadIdx.x & (DOUT - 1);
    int rg  = threadIdx.x >> 6;
    float bb = b[col];
    int r0 = blockIdx.x * 16 + rg * 4;
    #pragma unroll
    for (int rr = 0; rr < 4; ++rr) {
        int r = r0 + rr;
        if (r >= n_nodes) return;
        const uint2* hr = (const uint2*)(v2 + ((size_t)r << 7));
        float acc = bb;
        #pragma unroll
        for (int k4 = 0; k4 < 32; ++k4) {
            uint2 u = hr[k4];
            int k = k4 * 4;
            float f0 = bflo(u.x), f1 = bfhi(u.x), f2 = bflo(u.y), f3 = bfhi(u.y);
            float w0 = fmaxf(fmaf(f0, scs[k + 0], shs[k + 0]), 0.f);
            float w1 = fmaxf(fmaf(f1, scs[k + 1], shs[k + 1]), 0.f);
            float w2 = fmaxf(fmaf(f2, scs[k + 2], shs[k + 2]), 0.f);
            float w3 = fmaxf(fmaf(f3, scs[k + 3], shs[k + 3]), 0.f);
            acc = fmaf(w0, Ws[(k + 0) * DOUT + col], acc);
            acc = fmaf(w1, Ws[(k + 1) * DOUT + col], acc);
            acc = fmaf(w2, Ws[(k + 2) * DOUT + col], acc);
            acc = fmaf(w3, Ws[(k + 3) * DOUT + col], acc);
        }
        out[(size_t)r * DOUT + col] = acc;
    }
}

extern "C" void kernel_launch(void* const* d_in, const int* in_sizes, int n_in,
                              void* d_out, int out_size, void* d_ws, size_t ws_size,
                              hipStream_t stream) {
    const float* x     = (const float*)d_in[0];
    const int*   ei    = (const int*)d_in[1];
    const float* gamma = (const float*)d_in[2];
    const float* beta  = (const float*)d_in[3];
    const float* W     = (const float*)d_in[4];
    const float* bvec  = (const float*)d_in[5];
    float* out = (float*)d_out;

    const int n_nodes = in_sizes[0] / D;     // 100000
    const int n_edges = in_sizes[1] / 2;     // 1600000

    const size_t row_bytes = (size_t)n_nodes * D * sizeof(u16);   // 25.6 MB
    char* p = (char*)d_ws;
    u16*   xb     = (u16*)p;   p += row_bytes;
    u16*   vA     = (u16*)p;   p += row_bytes;
    u16*   vB     = (u16*)p;   p += row_bytes;
    int*   srcs   = (int*)p;   p += (size_t)n_edges * sizeof(int);
    int*   deg    = (int*)p;   p += (size_t)n_nodes * sizeof(int);
    int*   start  = (int*)p;   p += (size_t)n_nodes * sizeof(int);
    int*   cursor = (int*)p;   p += (size_t)n_nodes * sizeof(int);
    int*   counter= (int*)p;   p += 256;
    float* stats  = (float*)p; // 4 * 512 floats

    const float inv_n = 1.0f / (float)n_nodes;

    // --- init + CSR build + per-bucket sort (once per call) ---
    init_kernel<<<2048, 256, 0, stream>>>(x, xb, deg, counter, stats, n_nodes);
    hist_kernel<<<1024, 256, 0, stream>>>(ei, deg, n_edges);
    alloc_kernel<<<(n_nodes + 255) / 256, 256, 0, stream>>>(deg, start, cursor,
                                                            counter, n_nodes);
    fill_kernel<<<1024, 256, 0, stream>>>(ei, cursor, srcs, n_edges);
    sort_kernel<<<(n_nodes + 255) / 256, 256, 0, stream>>>(start, deg, srcs,
                                                           n_nodes);

    // --- 3 fused layers ---
    const u16* h = xb;
    u16* vout = vA;
    for (int L = 0; L < 3; ++L) {
        float* scur = stats + (size_t)(L + 1) * 512;
        const float* sprev = stats + (size_t)L * 512;
        if (L == 0)
            agg_kernel<false><<<2048, 256, 0, stream>>>(h, srcs, start, deg,
                sprev, scur, vout, n_nodes);
        else
            agg_kernel<true><<<2048, 256, 0, stream>>>(h, srcs, start, deg,
                sprev, scur, vout, n_nodes);
        finalize_stats_kernel<<<1, D, 0, stream>>>(scur, gamma, beta, L, inv_n);
        h = vout;
        vout = (vout == vA) ? vB : vA;
    }

    // --- head: inline norm of layer 2 + matmul ---
    head_kernel<<<(n_nodes + 15) / 16, 256, 0, stream>>>(h, stats + 3 * 512, W,
                                                         bvec, out, n_nodes);
}